// Round 14
// baseline (38.341 us; speedup 1.0000x reference)
//
#include <hip/hip_runtime.h>
#include <math.h>

#define OUT 14
#define RATIO 2
#define NS (OUT*RATIO)      // 28 sample positions per axis
#define NPIX (OUT*OUT)      // 196
#define C_TOT 256
#define CG 4                // channels per group (float4 interleave)
#define GPB 4               // groups per block, processed as 2 packed pairs
#define NCHUNK (C_TOT/(CG*GPB))   // 16
#define NBOX_PER_B 128
#define NTHREADS 256
#define PATCH_CAP 1280      // float4 slots per buffer; worst-case patch ~1043
#define MAXIT 5             // ceil(PATCH_CAP/NTHREADS)
#define NROI 256
#define NTASK (2*NPIX)      // 392 tasks per packed pair
#define NB (NTASK - NTHREADS)   // 136 round-B tasks

// ---------------------------------------------------------------------
// torchvision roi_align axis prep (must match reference op-for-op):
// valid = (c>-1)&(c<L); c=clip(c,0,L-1); lo=clip(floor(c),0,L-2); fr=c-lo
// ---------------------------------------------------------------------
__device__ __forceinline__ void prep_axis(float c, int L, int& lo, float& fh, float& fl)
{
    const bool  v  = (c > -1.0f) && (c < (float)L);
    const float cc = fminf(fmaxf(c, 0.0f), (float)(L - 1));
    const float fb = fminf(fmaxf(floorf(cc), 0.0f), (float)(L - 2));
    const float fr = cc - fb;
    lo = (int)fb;
    fl = v ? fr        : 0.0f;
    fh = v ? 1.0f - fr : 0.0f;
}

__device__ __forceinline__ int axis_lo(float c, int L)
{
    const float cc = fminf(fmaxf(c, 0.0f), (float)(L - 1));
    return (int)fminf(fmaxf(floorf(cc), 0.0f), (float)(L - 2));
}

// per-pixel tap state (R12 layout, no swizzle)
struct PixPrep { int rb0, rb1, cb0, cb1; float4 wy, wx; };

__device__ __forceinline__ PixPrep make_prep(int px, float y1, float bh, float x1, float bw,
                                             int H, int W, int ymin, int xmin, int stridep)
{
    PixPrep p;
    const int ph = px / OUT;
    const int pw = px - ph * OUT;
    int lo; float fh, fl;
    prep_axis(y1 + bh * (((float)(2*ph)   + 0.5f) * 0.5f), H, lo, fh, fl);
    p.rb0 = (lo - ymin) * stridep; p.wy.x = fh * 0.25f; p.wy.y = fl * 0.25f;
    prep_axis(y1 + bh * (((float)(2*ph+1) + 0.5f) * 0.5f), H, lo, fh, fl);
    p.rb1 = (lo - ymin) * stridep; p.wy.z = fh * 0.25f; p.wy.w = fl * 0.25f;
    prep_axis(x1 + bw * (((float)(2*pw)   + 0.5f) * 0.5f), W, lo, fh, fl);
    p.cb0 = lo - xmin; p.wx.x = fh; p.wx.y = fl;
    prep_axis(x1 + bw * (((float)(2*pw+1) + 0.5f) * 0.5f), W, lo, fh, fl);
    p.cb1 = lo - xmin; p.wx.z = fh; p.wx.w = fl;
    return p;
}

__device__ __forceinline__ float4 bilin16(const float4* __restrict__ sp,
                                          const PixPrep& p, int stridep)
{
    float4 acc = {0.0f, 0.0f, 0.0f, 0.0f};
    #pragma unroll
    for (int ys = 0; ys < 2; ++ys) {
        const int   rb = ys ? p.rb1 : p.rb0;
        const float yh = ys ? p.wy.z : p.wy.x;
        const float yl = ys ? p.wy.w : p.wy.y;
        #pragma unroll
        for (int xs = 0; xs < 2; ++xs) {
            const int base = rb + (xs ? p.cb1 : p.cb0);
            const float xh = xs ? p.wx.z : p.wx.x;
            const float xl = xs ? p.wx.w : p.wx.y;
            const float w00 = yh*xh, w01 = yh*xl, w10 = yl*xh, w11 = yl*xl;
            const float4 v00 = sp[base];
            const float4 v01 = sp[base + 1];
            const float4 v10 = sp[base + stridep];
            const float4 v11 = sp[base + stridep + 1];
            acc.x += w00*v00.x + w01*v01.x + w10*v10.x + w11*v11.x;
            acc.y += w00*v00.y + w01*v01.y + w10*v10.y + w11*v11.y;
            acc.z += w00*v00.z + w01*v01.z + w10*v10.z + w11*v11.z;
            acc.w += w00*v00.w + w01*v01.w + w10*v10.w + w11*v11.w;
        }
    }
    return acc;
}

// =====================================================================
// R12 structure (GPB=4, fused, amortized prologue, NO swizzle) with
// PACKED-PAIR compute: two 4-channel patches staged into two LDS
// buffers, then 392 (pixel,group) tasks over 256 threads:
//   round A: 256 tasks (100% lane efficiency)
//   round B: 136 tasks (g=hi, pixels 60..195)
// Wave-level ds_read_b128 count per pair: 112 vs 128 unpacked (-12.5%).
// LDS = 40960 B -> 4 blocks/CU (occupancy-insensitive per R6/R7).
// =====================================================================
__global__ __launch_bounds__(NTHREADS)
void roi_align_fusedp_kernel(const float* __restrict__ f0,
                             const float* __restrict__ f1,
                             const float* __restrict__ f2,
                             const float* __restrict__ f3,
                             const float* __restrict__ boxes,
                             float* __restrict__ out)
{
    const int chunk = blockIdx.x;   // 0..15
    const int k     = blockIdx.y;   // roi, 0..255
    const int tid   = threadIdx.x;

    __shared__ float4 s_patch[2*PATCH_CAP];   // 40960 B exactly

    // ---- per-roi params (uniform; computed redundantly, no LDS) ----
    const float bx1 = boxes[k*4+0];
    const float by1 = boxes[k*4+1];
    const float bx2 = boxes[k*4+2];
    const float by2 = boxes[k*4+3];

    const float wbox = bx2 - bx1;
    const float hbox = by2 - by1;
    const float sdim = sqrtf(wbox * hbox);
    float lvlf = floorf(4.0f + log2f(sdim / 224.0f + 1e-6f));
    lvlf = fminf(fmaxf(lvlf, 2.0f), 5.0f);
    const int lidx = (int)lvlf - 2;   // 0..3

    const float* fptr;
    int H, W;
    float scale;
    if      (lidx == 0) { fptr = f0; H = 200; W = 200; scale = 0.25f;    }
    else if (lidx == 1) { fptr = f1; H = 100; W = 100; scale = 0.125f;   }
    else if (lidx == 2) { fptr = f2; H = 50;  W = 50;  scale = 0.0625f;  }
    else                { fptr = f3; H = 25;  W = 25;  scale = 0.03125f; }

    const float x1 = bx1 * scale;
    const float y1 = by1 * scale;
    const float x2 = bx2 * scale;
    const float y2 = by2 * scale;
    const float rw = fmaxf(x2 - x1, 1.0f);
    const float rh = fmaxf(y2 - y1, 1.0f);
    const float bw = rw / (float)OUT;
    const float bh = rh / (float)OUT;

    // ---- patch extent from first/last sample (monotone tables) ----
    const float off0  = 0.25f;
    const float offL  = ((float)(NS-1) + 0.5f) * 0.5f;
    const int ymin  = axis_lo(y1 + bh * off0, H);
    const int xmin  = axis_lo(x1 + bw * off0, W);
    const int nrows = axis_lo(y1 + bh * offL, H) + 2 - ymin;
    const int ncols = axis_lo(x1 + bw * offL, W) + 2 - xmin;
    const int padded  = ncols | 1;
    const int stridep = (nrows * padded <= PATCH_CAP) ? padded : ncols;
    const int nelem   = nrows * ncols;
    const float rcpc  = 1.0f / (float)ncols;

    // ---- per-pixel tap state: round-A pixel (all lanes) + round-B pixel ----
    const int  pxA = (tid < NPIX) ? tid : tid - NPIX;   // 0..195 / 0..59
    const bool hiA = (tid >= NPIX);                     // lane serves hi group in round A
    const bool actB = (tid < NB);                       // 136 round-B lanes
    const int  pxB = tid + (NPIX - NB);                 // 60..195

    const PixPrep prA = make_prep(pxA, y1, bh, x1, bw, H, W, ymin, xmin, stridep);
    PixPrep prB;
    if (actB) prB = make_prep(pxB, y1, bh, x1, bw, H, W, ymin, xmin, stridep);

    // ---- staging coordinates (computed once, reused for all stages) ----
    const size_t plane = (size_t)H * (size_t)W;
    int go_[MAXIT], di_[MAXIT];
    #pragma unroll
    for (int t = 0; t < MAXIT; ++t) {
        const int i  = t*NTHREADS + tid;
        const int r  = (int)(((float)i + 0.5f) * rcpc);   // exact floor
        const int cc = i - r * ncols;
        const int di = r * stridep + cc;
        go_[t] = r * W + cc;
        di_[t] = (i < nelem && di < PATCH_CAP) ? di : -1;
    }

    const float* fbase = fptr
        + ((size_t)(k / NBOX_PER_B) * C_TOT + (size_t)chunk * (GPB*CG)) * plane
        + (size_t)ymin * W + xmin;
    float* outk = out + ((size_t)k * C_TOT + (size_t)chunk * (GPB*CG)) * NPIX;

    #pragma unroll
    for (int pair = 0; pair < 2; ++pair) {
        // ---- stage lo group -> buf0, hi group -> buf1 (interleaved issue) ----
        const float* a0 = fbase + (size_t)((2*pair)  *CG) * plane;
        const float* b0 = fbase + (size_t)((2*pair+1)*CG) * plane;
        #pragma unroll
        for (int t = 0; t < MAXIT; ++t) {
            if (di_[t] >= 0) {
                const int go = go_[t];
                float4 va, vb;
                va.x = a0[go];         vb.x = b0[go];
                va.y = a0[go+plane];   vb.y = b0[go+plane];
                va.z = a0[go+2*plane]; vb.z = b0[go+2*plane];
                va.w = a0[go+3*plane]; vb.w = b0[go+3*plane];
                s_patch[di_[t]]             = va;
                s_patch[di_[t] + PATCH_CAP] = vb;
            }
        }
        __syncthreads();

        // ---- round A: 256 tasks, 100% lane efficiency ----
        {
            const float4* sp = s_patch + (hiA ? PATCH_CAP : 0);
            const float4 acc = bilin16(sp, prA, stridep);
            const int lg = 2*pair + (hiA ? 1 : 0);
            float* ob = outk + (size_t)(lg*CG) * NPIX + pxA;
            ob[0*NPIX] = acc.x;
            ob[1*NPIX] = acc.y;
            ob[2*NPIX] = acc.z;
            ob[3*NPIX] = acc.w;
        }
        // ---- round B: 136 remaining tasks of the hi group ----
        if (actB) {
            const float4* sp = s_patch + PATCH_CAP;
            const float4 acc = bilin16(sp, prB, stridep);
            const int lg = 2*pair + 1;
            float* ob = outk + (size_t)(lg*CG) * NPIX + pxB;
            ob[0*NPIX] = acc.x;
            ob[1*NPIX] = acc.y;
            ob[2*NPIX] = acc.z;
            ob[3*NPIX] = acc.w;
        }
        if (pair == 0) __syncthreads();
    }
}

extern "C" void kernel_launch(void* const* d_in, const int* in_sizes, int n_in,
                              void* d_out, int out_size, void* d_ws, size_t ws_size,
                              hipStream_t stream) {
    const float* f0    = (const float*)d_in[0];
    const float* f1    = (const float*)d_in[1];
    const float* f2    = (const float*)d_in[2];
    const float* f3    = (const float*)d_in[3];
    const float* boxes = (const float*)d_in[4];
    float* out = (float*)d_out;

    dim3 grid(NCHUNK, NROI);   // 16 chunks x 256 rois (same-roi adjacent)
    roi_align_fusedp_kernel<<<grid, NTHREADS, 0, stream>>>(f0, f1, f2, f3, boxes, out);
}

// Round 15
// 37.379 us; speedup vs baseline: 1.0257x; 1.0257x over previous
//
#include <hip/hip_runtime.h>
#include <math.h>

#define OUT 14
#define RATIO 2
#define NS (OUT*RATIO)      // 28 sample positions per axis
#define NPIX (OUT*OUT)      // 196
#define C_TOT 256
#define CG 4                // channels per group (float4 interleave)
#define GPB 4               // groups per block (prologue amortization)
#define NCHUNK (C_TOT/(CG*GPB))   // 16
#define NBOX_PER_B 128
#define NTHREADS 256
#define PATCH_CAP 1280      // float4 slots; worst-case patch ~1043
#define MAXIT 5             // ceil(PATCH_CAP/NTHREADS)
#define NROI 256

// ---------------------------------------------------------------------
// torchvision roi_align axis prep (must match reference op-for-op):
// valid = (c>-1)&(c<L); c=clip(c,0,L-1); lo=clip(floor(c),0,L-2); fr=c-lo
// ---------------------------------------------------------------------
__device__ __forceinline__ void prep_axis(float c, int L, int& lo, float& fh, float& fl)
{
    const bool  v  = (c > -1.0f) && (c < (float)L);
    const float cc = fminf(fmaxf(c, 0.0f), (float)(L - 1));
    const float fb = fminf(fmaxf(floorf(cc), 0.0f), (float)(L - 2));
    const float fr = cc - fb;
    lo = (int)fb;
    fl = v ? fr        : 0.0f;
    fh = v ? 1.0f - fr : 0.0f;
}

__device__ __forceinline__ int axis_lo(float c, int L)
{
    const float cc = fminf(fmaxf(c, 0.0f), (float)(L - 1));
    return (int)fminf(fmaxf(floorf(cc), 0.0f), (float)(L - 2));
}

// =====================================================================
// Final kernel (R12 structure, best measured: 37.2 us).
// grid (16 chunks, 256 rois); each block owns GPB=4 four-channel groups
// of one roi. All roi-dependent VALU work (level transcendentals, patch
// extent, per-pixel sample prep, staging coordinates) is computed ONCE
// and reused across groups; per group: coalesced 4-channel float4-
// interleaved staging -> barrier -> 16 x ds_read_b128 taps + 64 FMA per
// pixel -> coalesced stores. LDS = 20480 B.
//
// Why this is the floor (measured): tap packing is at the 16B-read
// optimum (4 reads/pixel-channel); occupancy 34-77% shown time-invariant
// (R5/6/7/14); HBM warm traffic = writes only (14%); VALU cut 35% with
// no wall change (R12); LDS read count cut (R8) and conflict re-layout
// (R13) both regressed. LDS pipe ~65% busy incl. data-intrinsic
// conflicts; remainder is issue/latency interleave.
// =====================================================================
__global__ __launch_bounds__(NTHREADS)
void roi_align_fused4_kernel(const float* __restrict__ f0,
                             const float* __restrict__ f1,
                             const float* __restrict__ f2,
                             const float* __restrict__ f3,
                             const float* __restrict__ boxes,
                             float* __restrict__ out)
{
    const int chunk = blockIdx.x;   // 0..15
    const int k     = blockIdx.y;   // roi, 0..255
    const int tid   = threadIdx.x;

    __shared__ float4 s_patch[PATCH_CAP];   // 20480 B exactly

    // ---- per-roi params (uniform; computed redundantly, no LDS) ----
    const float bx1 = boxes[k*4+0];
    const float by1 = boxes[k*4+1];
    const float bx2 = boxes[k*4+2];
    const float by2 = boxes[k*4+3];

    const float wbox = bx2 - bx1;
    const float hbox = by2 - by1;
    const float sdim = sqrtf(wbox * hbox);
    float lvlf = floorf(4.0f + log2f(sdim / 224.0f + 1e-6f));
    lvlf = fminf(fmaxf(lvlf, 2.0f), 5.0f);
    const int lidx = (int)lvlf - 2;   // 0..3

    const float* fptr;
    int H, W;
    float scale;
    if      (lidx == 0) { fptr = f0; H = 200; W = 200; scale = 0.25f;    }
    else if (lidx == 1) { fptr = f1; H = 100; W = 100; scale = 0.125f;   }
    else if (lidx == 2) { fptr = f2; H = 50;  W = 50;  scale = 0.0625f;  }
    else                { fptr = f3; H = 25;  W = 25;  scale = 0.03125f; }

    const float x1 = bx1 * scale;
    const float y1 = by1 * scale;
    const float x2 = bx2 * scale;
    const float y2 = by2 * scale;
    const float rw = fmaxf(x2 - x1, 1.0f);
    const float rh = fmaxf(y2 - y1, 1.0f);
    const float bw = rw / (float)OUT;
    const float bh = rh / (float)OUT;

    // ---- patch extent from first/last sample (monotone tables) ----
    const float off0  = 0.25f;
    const float offL  = ((float)(NS-1) + 0.5f) * 0.5f;
    const int ymin  = axis_lo(y1 + bh * off0, H);
    const int xmin  = axis_lo(x1 + bw * off0, W);
    const int nrows = axis_lo(y1 + bh * offL, H) + 2 - ymin;
    const int ncols = axis_lo(x1 + bw * offL, W) + 2 - xmin;
    const int padded  = ncols | 1;
    const int stridep = (nrows * padded <= PATCH_CAP) ? padded : ncols;
    const int nelem   = nrows * ncols;
    const float rcpc  = 1.0f / (float)ncols;

    // ---- per-pixel tap state in registers (computed once) ----
    const bool active = (tid < NPIX);
    int rb0 = 0, rb1 = 0, cb0 = 0, cb1 = 0;
    float4 wy = {0,0,0,0};   // y weights * 0.25
    float4 wx = {0,0,0,0};   // x weights
    if (active) {
        const int ph = tid / OUT;
        const int pw = tid - ph * OUT;
        int lo; float fh, fl;
        prep_axis(y1 + bh * (((float)(2*ph)   + 0.5f) * 0.5f), H, lo, fh, fl);
        rb0 = (lo - ymin) * stridep; wy.x = fh * 0.25f; wy.y = fl * 0.25f;
        prep_axis(y1 + bh * (((float)(2*ph+1) + 0.5f) * 0.5f), H, lo, fh, fl);
        rb1 = (lo - ymin) * stridep; wy.z = fh * 0.25f; wy.w = fl * 0.25f;
        prep_axis(x1 + bw * (((float)(2*pw)   + 0.5f) * 0.5f), W, lo, fh, fl);
        cb0 = lo - xmin; wx.x = fh; wx.y = fl;
        prep_axis(x1 + bw * (((float)(2*pw+1) + 0.5f) * 0.5f), W, lo, fh, fl);
        cb1 = lo - xmin; wx.z = fh; wx.w = fl;
    }

    // ---- staging coordinates (computed once, reused for all groups) ----
    const size_t plane = (size_t)H * (size_t)W;
    int go_[MAXIT], di_[MAXIT];
    #pragma unroll
    for (int t = 0; t < MAXIT; ++t) {
        const int i  = t*NTHREADS + tid;
        const int r  = (int)(((float)i + 0.5f) * rcpc);   // exact floor
        const int cc = i - r * ncols;
        go_[t] = r * W + cc;
        di_[t] = (i < nelem && r * stridep + cc < PATCH_CAP) ? (r * stridep + cc) : -1;
    }

    const float* fbase = fptr
        + ((size_t)(k / NBOX_PER_B) * C_TOT + (size_t)chunk * (GPB*CG)) * plane
        + (size_t)ymin * W + xmin;
    float* outk = out + ((size_t)k * C_TOT + (size_t)chunk * (GPB*CG)) * NPIX;

    #pragma unroll
    for (int g = 0; g < GPB; ++g) {
        // ---- stage group g: 4 channels interleaved, coalesced ----
        const float* g0 = fbase + (size_t)(g*CG) * plane;
        const float* g1 = g0 +   plane;
        const float* g2 = g0 + 2*plane;
        const float* g3 = g0 + 3*plane;
        #pragma unroll
        for (int t = 0; t < MAXIT; ++t) {
            if (di_[t] >= 0) {
                const int go = go_[t];
                float4 v;
                v.x = g0[go]; v.y = g1[go]; v.z = g2[go]; v.w = g3[go];
                s_patch[di_[t]] = v;
            }
        }
        __syncthreads();

        // ---- bilinear: 16 x ds_read_b128, 64 FMA per pixel ----
        if (active) {
            float4 acc = {0.0f, 0.0f, 0.0f, 0.0f};
            #pragma unroll
            for (int ys = 0; ys < 2; ++ys) {
                const int   rb = ys ? rb1 : rb0;
                const float yh = ys ? wy.z : wy.x;
                const float yl = ys ? wy.w : wy.y;
                #pragma unroll
                for (int xs = 0; xs < 2; ++xs) {
                    const int base = rb + (xs ? cb1 : cb0);
                    const float xh = xs ? wx.z : wx.x;
                    const float xl = xs ? wx.w : wx.y;
                    const float w00 = yh*xh, w01 = yh*xl, w10 = yl*xh, w11 = yl*xl;
                    const float4 v00 = s_patch[base];
                    const float4 v01 = s_patch[base + 1];
                    const float4 v10 = s_patch[base + stridep];
                    const float4 v11 = s_patch[base + stridep + 1];
                    acc.x += w00*v00.x + w01*v01.x + w10*v10.x + w11*v11.x;
                    acc.y += w00*v00.y + w01*v01.y + w10*v10.y + w11*v11.y;
                    acc.z += w00*v00.z + w01*v01.z + w10*v10.z + w11*v11.z;
                    acc.w += w00*v00.w + w01*v01.w + w10*v10.w + w11*v11.w;
                }
            }
            float* ob = outk + (size_t)(g*CG) * NPIX + tid;
            ob[0*NPIX] = acc.x;
            ob[1*NPIX] = acc.y;
            ob[2*NPIX] = acc.z;
            ob[3*NPIX] = acc.w;
        }
        if (g + 1 < GPB) __syncthreads();
    }
}

extern "C" void kernel_launch(void* const* d_in, const int* in_sizes, int n_in,
                              void* d_out, int out_size, void* d_ws, size_t ws_size,
                              hipStream_t stream) {
    const float* f0    = (const float*)d_in[0];
    const float* f1    = (const float*)d_in[1];
    const float* f2    = (const float*)d_in[2];
    const float* f3    = (const float*)d_in[3];
    const float* boxes = (const float*)d_in[4];
    float* out = (float*)d_out;

    dim3 grid(NCHUNK, NROI);   // 16 chunks x 256 rois (same-roi adjacent)
    roi_align_fused4_kernel<<<grid, NTHREADS, 0, stream>>>(f0, f1, f2, f3, boxes, out);
}